// Round 1
// baseline (11681.177 us; speedup 1.0000x reference)
//
#include <hip/hip_runtime.h>

#define Bsz 2048
#define Ssz 96
#define Fsz 32
#define Hsz 256
#define Osz 6
#define LAsz 32

#define RT 16   // rows per block
#define CT 16   // h-channels per block

// ---------- accurate f64 exp (|rel err| ~1e-14), avoids slow libm path ----------
__device__ __forceinline__ double exp_d(double x) {
    x = fmin(fmax(x, -700.0), 700.0);
    const double LOG2E = 1.4426950408889634074;
    const double LN2HI = 6.93147180369123816490e-01;
    const double LN2LO = 1.90821492927058770002e-10;
    double n = __builtin_rint(x * LOG2E);
    double r = fma(-n, LN2HI, x);
    r = fma(-n, LN2LO, r);
    // Taylor to degree 11 on |r| <= 0.3466 -> rel err ~7e-15
    double p = 2.5052108385441718775e-08;          // 1/11!
    p = fma(p, r, 2.7557319223985890653e-07);      // 1/10!
    p = fma(p, r, 2.7557319223985892511e-06);      // 1/9!
    p = fma(p, r, 2.4801587301587301566e-05);      // 1/8!
    p = fma(p, r, 1.9841269841269841253e-04);      // 1/7!
    p = fma(p, r, 1.3888888888888889419e-03);      // 1/6!
    p = fma(p, r, 8.3333333333333332177e-03);      // 1/5!
    p = fma(p, r, 4.1666666666666664354e-02);      // 1/4!
    p = fma(p, r, 1.6666666666666665741e-01);      // 1/3!
    p = fma(p, r, 5.0e-01);
    p = fma(p, r, 1.0);
    p = fma(p, r, 1.0);
    long long bits = (long long)(1023 + (int)n) << 52;
    double s = __longlong_as_double(bits);
    return p * s;
}

__device__ __forceinline__ double sigmoid_d(double x) {
    return 1.0 / (1.0 + exp_d(-x));
}

__device__ __forceinline__ double tanh_d(double x) {
    double ax = fabs(x);
    double t = exp_d(-2.0 * ax);
    double r = (1.0 - t) / (1.0 + t);
    return x >= 0.0 ? r : -r;
}

// ---------- zero h0 and c ----------
__global__ void zero_state(double* __restrict__ p, size_t n) {
    size_t i = (size_t)blockIdx.x * 256 + threadIdx.x;
    if (i < n) p[i] = 0.0;
}

// ---------- one LSTM step (optionally look-ahead: replace x[:,0:6] with o, emit o) ----------
__global__ __launch_bounds__(256) void lstm_step(
    const float* __restrict__ x, const float* __restrict__ W_ih,
    const float* __restrict__ W_hh, const float* __restrict__ b_ih,
    const float* __restrict__ b_hh, const float* __restrict__ W_fc,
    const float* __restrict__ b_fc, const double* __restrict__ h_in,
    double* __restrict__ h_out, double* __restrict__ c,
    float* __restrict__ out, int t, int la_mode)
{
    __shared__ double h_lds[RT][Hsz + 1];
    __shared__ double x_lds[RT][Fsz];
    __shared__ double o_lds[RT][Osz];

    const int row0 = blockIdx.x * RT;
    const int j0   = blockIdx.y * CT;
    const int tid  = threadIdx.x;

    // stage h_in tile [RT x H]
    for (int i = tid; i < RT * Hsz; i += 256) {
        int r = i >> 8, col = i & (Hsz - 1);
        h_lds[r][col] = h_in[(size_t)(row0 + r) * Hsz + col];
    }
    // stage x[:, t, :] tile [RT x F]
    for (int i = tid; i < RT * Fsz; i += 256) {
        int r = i >> 5, col = i & (Fsz - 1);
        x_lds[r][col] = (double)x[((size_t)(row0 + r) * Ssz + t) * Fsz + col];
    }
    __syncthreads();

    if (la_mode) {
        // o = binarize(h_in) @ W_fc.T + b_fc  (computed redundantly per channel-block)
        if (tid < RT * Osz) {
            int r = tid / Osz, oo = tid % Osz;
            double acc = (double)b_fc[oo];
            const float* wf = W_fc + oo * Hsz;
            for (int k = 0; k < Hsz; ++k)
                acc += (h_lds[r][k] > 0.0 ? (double)wf[k] : 0.0);
            o_lds[r][oo] = acc;
            if (blockIdx.y == 0)
                out[(size_t)(row0 + r) * (LAsz + 1) * Osz + (size_t)t * Osz + oo] = (float)acc;
        }
        __syncthreads();
        if (tid < RT * Osz) {
            int r = tid / Osz, oo = tid % Osz;
            x_lds[r][oo] = o_lds[r][oo];   // RS=0, RE=6
        }
        __syncthreads();
    }

    // gates for (row r, channel jg): i,f,g,o rows of W at jg, H+jg, 2H+jg, 3H+jg
    const int r   = tid & (RT - 1);
    const int j   = tid >> 4;
    const int jg  = j0 + j;
    const int row = row0 + r;

    double ai = (double)b_ih[0 * Hsz + jg] + (double)b_hh[0 * Hsz + jg];
    double af = (double)b_ih[1 * Hsz + jg] + (double)b_hh[1 * Hsz + jg];
    double ag = (double)b_ih[2 * Hsz + jg] + (double)b_hh[2 * Hsz + jg];
    double ao = (double)b_ih[3 * Hsz + jg] + (double)b_hh[3 * Hsz + jg];

    const float* wi_i = W_ih + (size_t)(0 * Hsz + jg) * Fsz;
    const float* wi_f = W_ih + (size_t)(1 * Hsz + jg) * Fsz;
    const float* wi_g = W_ih + (size_t)(2 * Hsz + jg) * Fsz;
    const float* wi_o = W_ih + (size_t)(3 * Hsz + jg) * Fsz;
    #pragma unroll 8
    for (int k = 0; k < Fsz; ++k) {
        double xv = x_lds[r][k];
        ai = fma(xv, (double)wi_i[k], ai);
        af = fma(xv, (double)wi_f[k], af);
        ag = fma(xv, (double)wi_g[k], ag);
        ao = fma(xv, (double)wi_o[k], ao);
    }

    const float* wh_i = W_hh + (size_t)(0 * Hsz + jg) * Hsz;
    const float* wh_f = W_hh + (size_t)(1 * Hsz + jg) * Hsz;
    const float* wh_g = W_hh + (size_t)(2 * Hsz + jg) * Hsz;
    const float* wh_o = W_hh + (size_t)(3 * Hsz + jg) * Hsz;
    for (int k = 0; k < Hsz; k += 4) {
        float4 w_i = *(const float4*)(wh_i + k);
        float4 w_f = *(const float4*)(wh_f + k);
        float4 w_g = *(const float4*)(wh_g + k);
        float4 w_o = *(const float4*)(wh_o + k);
        double h0v = h_lds[r][k + 0];
        double h1v = h_lds[r][k + 1];
        double h2v = h_lds[r][k + 2];
        double h3v = h_lds[r][k + 3];
        ai = fma(h0v, (double)w_i.x, ai); ai = fma(h1v, (double)w_i.y, ai);
        ai = fma(h2v, (double)w_i.z, ai); ai = fma(h3v, (double)w_i.w, ai);
        af = fma(h0v, (double)w_f.x, af); af = fma(h1v, (double)w_f.y, af);
        af = fma(h2v, (double)w_f.z, af); af = fma(h3v, (double)w_f.w, af);
        ag = fma(h0v, (double)w_g.x, ag); ag = fma(h1v, (double)w_g.y, ag);
        ag = fma(h2v, (double)w_g.z, ag); ag = fma(h3v, (double)w_g.w, ag);
        ao = fma(h0v, (double)w_o.x, ao); ao = fma(h1v, (double)w_o.y, ao);
        ao = fma(h2v, (double)w_o.z, ao); ao = fma(h3v, (double)w_o.w, ao);
    }

    double si = sigmoid_d(ai);
    double sf = sigmoid_d(af);
    double tg = tanh_d(ag);
    double so = sigmoid_d(ao);

    size_t cidx = (size_t)row * Hsz + jg;
    double cv = c[cidx];
    double cn = fma(sf, cv, si * tg);
    double hn = so * tanh_d(cn);
    c[cidx] = cn;
    h_out[cidx] = hn;
}

// ---------- final readout: outputs[:, 32, :] ----------
__global__ void final_out(const double* __restrict__ h,
                          const float* __restrict__ W_fc,
                          const float* __restrict__ b_fc,
                          float* __restrict__ out)
{
    int i = blockIdx.x * 256 + threadIdx.x;
    if (i >= Bsz * Osz) return;
    int row = i / Osz, oo = i % Osz;
    double acc = (double)b_fc[oo];
    const float* wf = W_fc + oo * Hsz;
    const double* hr = h + (size_t)row * Hsz;
    for (int k = 0; k < Hsz; ++k)
        acc += (hr[k] > 0.0 ? (double)wf[k] : 0.0);
    out[(size_t)row * (LAsz + 1) * Osz + (size_t)LAsz * Osz + oo] = (float)acc;
}

extern "C" void kernel_launch(void* const* d_in, const int* in_sizes, int n_in,
                              void* d_out, int out_size, void* d_ws, size_t ws_size,
                              hipStream_t stream)
{
    const float* x    = (const float*)d_in[0];
    const float* W_ih = (const float*)d_in[1];
    const float* W_hh = (const float*)d_in[2];
    const float* b_ih = (const float*)d_in[3];
    const float* b_hh = (const float*)d_in[4];
    const float* W_fc = (const float*)d_in[5];
    const float* b_fc = (const float*)d_in[6];
    float* out = (float*)d_out;

    double* c  = (double*)d_ws;                 // [B*H]
    double* h0 = c + (size_t)Bsz * Hsz;         // [B*H]
    double* h1 = h0 + (size_t)Bsz * Hsz;        // [B*H]

    // zero c and h0 (contiguous)
    size_t nz = (size_t)Bsz * Hsz * 2;
    zero_state<<<dim3((unsigned)((nz + 255) / 256)), dim3(256), 0, stream>>>(c, nz);

    dim3 grid(Bsz / RT, Hsz / CT), block(256);
    const double* hin = h0;
    double* hout = h1;

    for (int t = 0; t < Ssz; ++t) {
        lstm_step<<<grid, block, 0, stream>>>(x, W_ih, W_hh, b_ih, b_hh, W_fc, b_fc,
                                              hin, hout, c, out, t, 0);
        const double* tmp = hout; hout = (double*)hin; hin = tmp;
    }
    for (int t = 0; t < LAsz; ++t) {
        lstm_step<<<grid, block, 0, stream>>>(x, W_ih, W_hh, b_ih, b_hh, W_fc, b_fc,
                                              hin, hout, c, out, t, 1);
        const double* tmp = hout; hout = (double*)hin; hin = tmp;
    }
    final_out<<<dim3((Bsz * Osz + 255) / 256), dim3(256), 0, stream>>>(hin, W_fc, b_fc, out);
}

// Round 2
// 5898.056 us; speedup vs baseline: 1.9805x; 1.9805x over previous
//
#include <hip/hip_runtime.h>

#define Bsz 2048
#define Ssz 96
#define Fsz 32
#define Hsz 256
#define Osz 6
#define LAsz 32
#define RT 8                  // batch rows per block; grid = 2048/8 = 256 = 1 block/CU
#define NSTEP (Ssz + LAsz)

// ---------- accurate f64 exp (|rel err| ~1e-14) ----------
__device__ __forceinline__ double exp_d(double x) {
    x = fmin(fmax(x, -700.0), 700.0);
    const double LOG2E = 1.4426950408889634074;
    const double LN2HI = 6.93147180369123816490e-01;
    const double LN2LO = 1.90821492927058770002e-10;
    double n = __builtin_rint(x * LOG2E);
    double r = fma(-n, LN2HI, x);
    r = fma(-n, LN2LO, r);
    double p = 2.5052108385441718775e-08;
    p = fma(p, r, 2.7557319223985890653e-07);
    p = fma(p, r, 2.7557319223985892511e-06);
    p = fma(p, r, 2.4801587301587301566e-05);
    p = fma(p, r, 1.9841269841269841253e-04);
    p = fma(p, r, 1.3888888888888889419e-03);
    p = fma(p, r, 8.3333333333333332177e-03);
    p = fma(p, r, 4.1666666666666664354e-02);
    p = fma(p, r, 1.6666666666666665741e-01);
    p = fma(p, r, 5.0e-01);
    p = fma(p, r, 1.0);
    p = fma(p, r, 1.0);
    long long bits = (long long)(1023 + (int)n) << 52;
    return p * __longlong_as_double(bits);
}
__device__ __forceinline__ double sigmoid_d(double x) { return 1.0 / (1.0 + exp_d(-x)); }
__device__ __forceinline__ double tanh_d(double x) {
    double ax = fabs(x);
    double t = exp_d(-2.0 * ax);
    double r = (1.0 - t) / (1.0 + t);
    return x >= 0.0 ? r : -r;
}

// 8 ascending-k FMAs into one accumulator (order matches round-1 kernel)
#define DOT8(accv, WA, WB)                              \
    accv = fma((double)WA.x, h01.x, accv);              \
    accv = fma((double)WA.y, h01.y, accv);              \
    accv = fma((double)WA.z, h23.x, accv);              \
    accv = fma((double)WA.w, h23.y, accv);              \
    accv = fma((double)WB.x, h45.x, accv);              \
    accv = fma((double)WB.y, h45.y, accv);              \
    accv = fma((double)WB.z, h67.x, accv);              \
    accv = fma((double)WB.w, h67.y, accv);

__global__ __launch_bounds__(256, 1) void lstm_persist(
    const float* __restrict__ x, const float* __restrict__ W_ih,
    const float* __restrict__ W_hh, const float* __restrict__ b_ih,
    const float* __restrict__ b_hh, const float* __restrict__ W_fc,
    const float* __restrict__ b_fc, float* __restrict__ out)
{
    __shared__ __align__(16) double h_lds[RT][Hsz];     // 16 KB
    __shared__ __align__(16) double x_lds[RT][Fsz];     // 2 KB
    __shared__ double o_lds[RT][Osz];
    __shared__ double ored[RT][Osz][4];
    __shared__ float  wfc_lds[Osz * Hsz];               // 6 KB

    const int tid  = threadIdx.x;
    const int row0 = blockIdx.x * RT;
    const int j    = tid;                                // h-channel owned by this thread

    for (int i = tid; i < RT * Hsz; i += 256) ((double*)h_lds)[i] = 0.0;
    for (int i = tid; i < Osz * Hsz; i += 256) wfc_lds[i] = W_fc[i];

    const float* wih0 = W_ih + (size_t)(0 * Hsz + j) * Fsz;
    const float* wih1 = W_ih + (size_t)(1 * Hsz + j) * Fsz;
    const float* wih2 = W_ih + (size_t)(2 * Hsz + j) * Fsz;
    const float* wih3 = W_ih + (size_t)(3 * Hsz + j) * Fsz;
    const float* whh0 = W_hh + (size_t)(0 * Hsz + j) * Hsz;
    const float* whh1 = W_hh + (size_t)(1 * Hsz + j) * Hsz;
    const float* whh2 = W_hh + (size_t)(2 * Hsz + j) * Hsz;
    const float* whh3 = W_hh + (size_t)(3 * Hsz + j) * Hsz;

    const double bias0 = (double)b_ih[0 * Hsz + j] + (double)b_hh[0 * Hsz + j];
    const double bias1 = (double)b_ih[1 * Hsz + j] + (double)b_hh[1 * Hsz + j];
    const double bias2 = (double)b_ih[2 * Hsz + j] + (double)b_hh[2 * Hsz + j];
    const double bias3 = (double)b_ih[3 * Hsz + j] + (double)b_hh[3 * Hsz + j];

    double c_reg[RT];
    #pragma unroll
    for (int r = 0; r < RT; ++r) c_reg[r] = 0.0;

    __syncthreads();

    for (int t = 0; t < NSTEP; ++t) {
        // ---- stage x[:, t (or t-Ssz), :] ----
        {
            int r = tid >> 5, f = tid & 31;
            int ts = (t < Ssz) ? t : (t - Ssz);
            x_lds[r][f] = (double)x[((size_t)(row0 + r) * Ssz + ts) * Fsz + f];
        }
        __syncthreads();
        if (t >= Ssz) {                                  // replace features 0..5 with o
            if (tid < RT * Osz) {
                int r = tid / Osz, oo = tid - r * Osz;
                x_lds[r][oo] = o_lds[r][oo];
            }
            __syncthreads();
        }

        double acc[4][RT];
        #pragma unroll
        for (int r = 0; r < RT; ++r) {
            acc[0][r] = bias0; acc[1][r] = bias1; acc[2][r] = bias2; acc[3][r] = bias3;
        }

        // ---- F part: gates += W_ih . x ----
        #pragma unroll 1
        for (int k0 = 0; k0 < Fsz; k0 += 8) {
            float4 wa[4], wb[4];
            wa[0] = *(const float4*)(wih0 + k0); wb[0] = *(const float4*)(wih0 + k0 + 4);
            wa[1] = *(const float4*)(wih1 + k0); wb[1] = *(const float4*)(wih1 + k0 + 4);
            wa[2] = *(const float4*)(wih2 + k0); wb[2] = *(const float4*)(wih2 + k0 + 4);
            wa[3] = *(const float4*)(wih3 + k0); wb[3] = *(const float4*)(wih3 + k0 + 4);
            #pragma unroll
            for (int r = 0; r < RT; ++r) {
                double2 h01 = *(const double2*)&x_lds[r][k0];
                double2 h23 = *(const double2*)&x_lds[r][k0 + 2];
                double2 h45 = *(const double2*)&x_lds[r][k0 + 4];
                double2 h67 = *(const double2*)&x_lds[r][k0 + 6];
                DOT8(acc[0][r], wa[0], wb[0]);
                DOT8(acc[1][r], wa[1], wb[1]);
                DOT8(acc[2][r], wa[2], wb[2]);
                DOT8(acc[3][r], wa[3], wb[3]);
            }
        }

        // ---- H part: gates += W_hh . h  (next-chunk weight prefetch) ----
        {
            float4 wa[4], wb[4], na[4], nb[4];
            wa[0] = *(const float4*)(whh0); wb[0] = *(const float4*)(whh0 + 4);
            wa[1] = *(const float4*)(whh1); wb[1] = *(const float4*)(whh1 + 4);
            wa[2] = *(const float4*)(whh2); wb[2] = *(const float4*)(whh2 + 4);
            wa[3] = *(const float4*)(whh3); wb[3] = *(const float4*)(whh3 + 4);
            #pragma unroll 1
            for (int k0 = 0; k0 < Hsz; k0 += 8) {
                int kn = (k0 + 8 < Hsz) ? (k0 + 8) : 0;
                na[0] = *(const float4*)(whh0 + kn); nb[0] = *(const float4*)(whh0 + kn + 4);
                na[1] = *(const float4*)(whh1 + kn); nb[1] = *(const float4*)(whh1 + kn + 4);
                na[2] = *(const float4*)(whh2 + kn); nb[2] = *(const float4*)(whh2 + kn + 4);
                na[3] = *(const float4*)(whh3 + kn); nb[3] = *(const float4*)(whh3 + kn + 4);
                #pragma unroll
                for (int r = 0; r < RT; ++r) {
                    double2 h01 = *(const double2*)&h_lds[r][k0];
                    double2 h23 = *(const double2*)&h_lds[r][k0 + 2];
                    double2 h45 = *(const double2*)&h_lds[r][k0 + 4];
                    double2 h67 = *(const double2*)&h_lds[r][k0 + 6];
                    DOT8(acc[0][r], wa[0], wb[0]);
                    DOT8(acc[1][r], wa[1], wb[1]);
                    DOT8(acc[2][r], wa[2], wb[2]);
                    DOT8(acc[3][r], wa[3], wb[3]);
                }
                #pragma unroll
                for (int g = 0; g < 4; ++g) { wa[g] = na[g]; wb[g] = nb[g]; }
            }
        }

        __syncthreads();   // all h_lds/x_lds reads complete

        // ---- activations; update c (regs) and h (LDS) ----
        double hnew[RT];
        #pragma unroll
        for (int r = 0; r < RT; ++r) {
            double si = sigmoid_d(acc[0][r]);
            double sf = sigmoid_d(acc[1][r]);
            double tg = tanh_d(acc[2][r]);
            double so = sigmoid_d(acc[3][r]);
            double cn = fma(sf, c_reg[r], si * tg);
            c_reg[r] = cn;
            hnew[r]  = so * tanh_d(cn);
        }
        #pragma unroll
        for (int r = 0; r < RT; ++r) h_lds[r][j] = hnew[r];

        // ---- readout (post-warm-up and every LA step) ----
        if (t >= Ssz - 1) {
            __syncthreads();                              // h_lds complete
            if (tid < 192) {                              // 8 rows x 6 outs x 4 segments
                int r = tid / 24, rem = tid % 24, oo = rem >> 2, seg = rem & 3;
                const float* wf = wfc_lds + oo * Hsz + seg * 64;
                const double* hr = &h_lds[r][seg * 64];
                double a = 0.0;
                #pragma unroll 4
                for (int k = 0; k < 64; ++k) a += (hr[k] > 0.0) ? (double)wf[k] : 0.0;
                ored[r][oo][seg] = a;
            }
            __syncthreads();
            if (tid < RT * Osz) {
                int r = tid / Osz, oo = tid - r * Osz;
                double o = (double)b_fc[oo] + ored[r][oo][0] + ored[r][oo][1]
                                            + ored[r][oo][2] + ored[r][oo][3];
                o_lds[r][oo] = o;
                out[((size_t)(row0 + r) * (LAsz + 1) + (t - (Ssz - 1))) * Osz + oo] = (float)o;
            }
        }
        __syncthreads();   // h_lds (and o_lds) published for next step
    }
}

extern "C" void kernel_launch(void* const* d_in, const int* in_sizes, int n_in,
                              void* d_out, int out_size, void* d_ws, size_t ws_size,
                              hipStream_t stream)
{
    const float* x    = (const float*)d_in[0];
    const float* W_ih = (const float*)d_in[1];
    const float* W_hh = (const float*)d_in[2];
    const float* b_ih = (const float*)d_in[3];
    const float* b_hh = (const float*)d_in[4];
    const float* W_fc = (const float*)d_in[5];
    const float* b_fc = (const float*)d_in[6];
    float* out = (float*)d_out;

    lstm_persist<<<dim3(Bsz / RT), dim3(256), 0, stream>>>(
        x, W_ih, W_hh, b_ih, b_hh, W_fc, b_fc, out);
}